// Round 1
// baseline (1068.740 us; speedup 1.0000x reference)
//
#include <hip/hip_runtime.h>
#include <math.h>

#define HH 256
#define WW 256
#define HW 65536

__device__ __forceinline__ float lrelu_f(float v) { return v > 0.f ? v : 0.2f * v; }

// ---- weight repack: w[O=32][IC][KK] -> wr[IC*KK][32] ----
__global__ __launch_bounds__(256) void repack_w(const float* __restrict__ w,
                                                float* __restrict__ wr, int IC, int KK) {
  int total = 32 * IC * KK;
  for (int i = blockIdx.x * blockDim.x + threadIdx.x; i < total; i += gridDim.x * blockDim.x) {
    int o = i / (IC * KK);
    int r = i - o * (IC * KK);
    wr[r * 32 + o] = w[i];
  }
}

// ---- bicubic 2x upsample: (2,3,128,128) -> (2,3,256,256) ----
__global__ __launch_bounds__(256) void up2_kernel(const float* __restrict__ q,
                                                  float* __restrict__ out) {
  int gid = blockIdx.x * blockDim.x + threadIdx.x;
  if (gid >= 2 * 3 * HW) return;
  int x = gid & 255;
  int y = (gid >> 8) & 255;
  int pc = gid >> 16;  // b*3+c
  const float F[4] = {-0.03515625f, 0.26171875f, 0.87890625f, -0.10546875f};
  int iy[4], ix[4];
  float wy[4], wx[4];
  {
    int k = y >> 1; bool even = !(y & 1); int i0 = even ? k - 1 : k;
#pragma unroll
    for (int t = 0; t < 4; ++t) {
      int ii = i0 - 1 + t;
      iy[t] = min(max(ii, 0), 127);
      wy[t] = even ? F[t] : F[3 - t];
    }
  }
  {
    int k = x >> 1; bool even = !(x & 1); int i0 = even ? k - 1 : k;
#pragma unroll
    for (int t = 0; t < 4; ++t) {
      int ii = i0 - 1 + t;
      ix[t] = min(max(ii, 0), 127);
      wx[t] = even ? F[t] : F[3 - t];
    }
  }
  const float* qp = q + pc * 16384;
  float s = 0.f;
#pragma unroll
  for (int i = 0; i < 4; ++i) {
    float rs = 0.f;
#pragma unroll
    for (int j = 0; j < 4; ++j) rs = fmaf(wx[j], qp[iy[i] * 128 + ix[j]], rs);
    s = fmaf(wy[i], rs, s);
  }
  out[gid] = s;
}

// ---- conv 5x5, IC=3 -> 32, pad 2, + lrelu ----
__global__ __launch_bounds__(256) void conv5_c1(const float* __restrict__ in,
                                                const float* __restrict__ wr,
                                                const float* __restrict__ bias,
                                                float* __restrict__ out) {
  __shared__ float s[3][20][20];
  int blk = blockIdx.x;
  int b = blk >> 8;
  int t = blk & 255;
  int ty0 = (t >> 4) * 16, tx0 = (t & 15) * 16;
  int tid = threadIdx.x;
  for (int i = tid; i < 3 * 400; i += 256) {
    int ic = i / 400;
    int r = i - ic * 400;
    int yy = r / 20, xx = r - (r / 20) * 20;
    int gy = ty0 + yy - 2, gx = tx0 + xx - 2;
    float v = 0.f;
    if ((unsigned)gy < 256u && (unsigned)gx < 256u) v = in[(b * 3 + ic) * HW + gy * 256 + gx];
    s[ic][yy][xx] = v;
  }
  __syncthreads();
  int ty = tid >> 4, tx = tid & 15;
  float acc[32];
#pragma unroll
  for (int o = 0; o < 32; ++o) acc[o] = bias[o];
  for (int ic = 0; ic < 3; ++ic) {
#pragma unroll
    for (int ky = 0; ky < 5; ++ky)
#pragma unroll
      for (int kx = 0; kx < 5; ++kx) {
        float v = s[ic][ty + ky][tx + kx];
        const float* wp = wr + (ic * 25 + ky * 5 + kx) * 32;
#pragma unroll
        for (int o = 0; o < 32; ++o) acc[o] = fmaf(v, wp[o], acc[o]);
      }
  }
  int y = ty0 + ty, x = tx0 + tx;
#pragma unroll
  for (int o = 0; o < 32; ++o) out[(b * 32 + o) * HW + y * 256 + x] = lrelu_f(acc[o]);
}

// ---- conv 3x3, 32 -> 32, pad 1, optional residual, lrelu ----
template <bool RES>
__global__ __launch_bounds__(256) void conv3_32(const float* __restrict__ in, int in_cs,
                                                const float* __restrict__ wr,
                                                const float* __restrict__ bias,
                                                const float* __restrict__ res,
                                                float* __restrict__ out, int out_cs,
                                                int out_co) {
  __shared__ float s[32][18][18];
  int blk = blockIdx.x;
  int b = blk >> 8;
  int t = blk & 255;
  int ty0 = (t >> 4) * 16, tx0 = (t & 15) * 16;
  int tid = threadIdx.x;
  for (int i = tid; i < 32 * 324; i += 256) {
    int ic = i / 324;
    int r = i - ic * 324;
    int yy = r / 18, xx = r - (r / 18) * 18;
    int gy = ty0 + yy - 1, gx = tx0 + xx - 1;
    float v = 0.f;
    if ((unsigned)gy < 256u && (unsigned)gx < 256u)
      v = in[(b * in_cs + ic) * HW + gy * 256 + gx];
    s[ic][yy][xx] = v;
  }
  __syncthreads();
  int ty = tid >> 4, tx = tid & 15;
  float acc[32];
#pragma unroll
  for (int o = 0; o < 32; ++o) acc[o] = bias[o];
  for (int ic = 0; ic < 32; ++ic) {
#pragma unroll
    for (int ky = 0; ky < 3; ++ky)
#pragma unroll
      for (int kx = 0; kx < 3; ++kx) {
        float v = s[ic][ty + ky][tx + kx];
        const float* wp = wr + (ic * 9 + ky * 3 + kx) * 32;
#pragma unroll
        for (int o = 0; o < 32; ++o) acc[o] = fmaf(v, wp[o], acc[o]);
      }
  }
  int y = ty0 + ty, x = tx0 + tx;
#pragma unroll
  for (int o = 0; o < 32; ++o) {
    float r = acc[o];
    if (RES) r += res[(b * 32 + o) * HW + y * 256 + x];
    out[(b * out_cs + out_co + o) * HW + y * 256 + x] = lrelu_f(r);
  }
}

// ---- conv 5x5, 64 -> 32, pad 2, + lrelu (ic chunked by 16) ----
__global__ __launch_bounds__(256) void conv5_p1(const float* __restrict__ in,
                                                const float* __restrict__ wr,
                                                const float* __restrict__ bias,
                                                float* __restrict__ out) {
  __shared__ float s[16][20][20];
  int blk = blockIdx.x;
  int b = blk >> 8;
  int t = blk & 255;
  int ty0 = (t >> 4) * 16, tx0 = (t & 15) * 16;
  int tid = threadIdx.x;
  int ty = tid >> 4, tx = tid & 15;
  float acc[32];
#pragma unroll
  for (int o = 0; o < 32; ++o) acc[o] = bias[o];
  for (int ch = 0; ch < 4; ++ch) {
    __syncthreads();
    for (int i = tid; i < 16 * 400; i += 256) {
      int ic = i / 400;
      int r = i - ic * 400;
      int yy = r / 20, xx = r - (r / 20) * 20;
      int gy = ty0 + yy - 2, gx = tx0 + xx - 2;
      float v = 0.f;
      if ((unsigned)gy < 256u && (unsigned)gx < 256u)
        v = in[(b * 64 + ch * 16 + ic) * HW + gy * 256 + gx];
      s[ic][yy][xx] = v;
    }
    __syncthreads();
    for (int ic = 0; ic < 16; ++ic) {
#pragma unroll
      for (int ky = 0; ky < 5; ++ky)
#pragma unroll
        for (int kx = 0; kx < 5; ++kx) {
          float v = s[ic][ty + ky][tx + kx];
          const float* wp = wr + ((ch * 16 + ic) * 25 + ky * 5 + kx) * 32;
#pragma unroll
          for (int o = 0; o < 32; ++o) acc[o] = fmaf(v, wp[o], acc[o]);
        }
    }
  }
  int y = ty0 + ty, x = tx0 + tx;
#pragma unroll
  for (int o = 0; o < 32; ++o) out[(b * 32 + o) * HW + y * 256 + x] = lrelu_f(acc[o]);
}

// ---- 1x1 conv 32->3, +1, clip, -> per-pixel sampling params ----
__global__ __launch_bounds__(256) void p2_aff(const float* __restrict__ h2,
                                              const float* __restrict__ w,
                                              const float* __restrict__ bias,
                                              float4* __restrict__ par) {
  int gid = blockIdx.x * 256 + threadIdx.x;  // 131072
  int b = gid >> 16;
  int p = gid & 65535;
  float a0 = bias[0], a1 = bias[1], a2 = bias[2];
  for (int c = 0; c < 32; ++c) {
    float v = h2[(b * 32 + c) * HW + p];
    a0 = fmaf(v, w[c], a0);
    a1 = fmaf(v, w[32 + c], a1);
    a2 = fmaf(v, w[64 + c], a2);
  }
  a0 = fminf(fmaxf(a0 + 1.f, -3.f), 3.f);
  a1 = fminf(fmaxf(a1 + 1.f, -3.f), 3.f);
  a2 = fminf(fmaxf(a2 + 1.f, -3.f), 3.f);
  float th = (a2 - 1.f) * 1.0472f;
  float4 o;
  o.x = a0;
  o.y = a1;
  o.z = cosf(th);
  o.w = sinf(th);
  par[gid] = o;
}

__device__ __forceinline__ int refl_idx(int k) {
  int s = k - 1;
  s = s < 0 ? -s : s;
  s = s > 255 ? 510 - s : s;
  return s;
}

// ---- deformable 3x3 bilinear sampling -> out (2,32,768,768) ----
__global__ __launch_bounds__(256) void sample_kernel(const float* __restrict__ x,
                                                     const float4* __restrict__ par,
                                                     float* __restrict__ out) {
  int gid = blockIdx.x * 256 + threadIdx.x;  // 131072
  int b = gid >> 16;
  int p = gid & 65535;
  int y = p >> 8;
  int xw = p & 255;
  float4 pr = par[gid];
  float sx = pr.x, sy = pr.y, ct = pr.z, st = pr.w;
  const float vals[3] = {-1.5f, -0.5f, 0.5f};
  int off[9][4];
  float g[9][4];
#pragma unroll
  for (int ki = 0; ki < 3; ++ki)
#pragma unroll
    for (int kj = 0; kj < 3; ++kj) {
      int n = ki * 3 + kj;
      float px0 = vals[ki] * sx, py0 = vals[kj] * sy;
      float px = px0 * ct - py0 * st + 1.5f + (float)(y + 1);
      float py = px0 * st + py0 * ct + 1.5f + (float)(xw + 1);
      float fx = floorf(px), fy = floorf(py);
      float x0f = fminf(fmaxf(fx, 0.f), 257.f);
      float x1f = fminf(fmaxf(fx + 1.f, 0.f), 257.f);
      float y0f = fminf(fmaxf(fy, 0.f), 257.f);
      float y1f = fminf(fmaxf(fy + 1.f, 0.f), 257.f);
      float pxc = fminf(fmaxf(px, 0.f), 257.f);
      float pyc = fminf(fmaxf(py, 0.f), 257.f);
      float dx0 = 1.f + (x0f - pxc), dx1 = 1.f - (x1f - pxc);
      float dy0 = 1.f + (y0f - pyc), dy1 = 1.f - (y1f - pyc);
      g[n][0] = dx0 * dy0;  // lt
      g[n][1] = dx1 * dy1;  // rb
      g[n][2] = dx0 * dy1;  // lb
      g[n][3] = dx1 * dy0;  // rt
      int xi0 = refl_idx((int)x0f), xi1 = refl_idx((int)x1f);
      int yi0 = refl_idx((int)y0f), yi1 = refl_idx((int)y1f);
      off[n][0] = xi0 * 256 + yi0;
      off[n][1] = xi1 * 256 + yi1;
      off[n][2] = xi0 * 256 + yi1;
      off[n][3] = xi1 * 256 + yi0;
    }
  for (int c = 0; c < 32; ++c) {
    const float* xp = x + (size_t)(b * 32 + c) * HW;
    float* op = out + ((size_t)(b * 32 + c) * 768 + 3 * y) * 768 + 3 * xw;
#pragma unroll
    for (int ki = 0; ki < 3; ++ki) {
#pragma unroll
      for (int kj = 0; kj < 3; ++kj) {
        int n = ki * 3 + kj;
        float v = g[n][0] * xp[off[n][0]] + g[n][1] * xp[off[n][1]] +
                  g[n][2] * xp[off[n][2]] + g[n][3] * xp[off[n][3]];
        op[ki * 768 + kj] = v;
      }
    }
  }
}

extern "C" void kernel_launch(void* const* d_in, const int* in_sizes, int n_in,
                              void* d_out, int out_size, void* d_ws, size_t ws_size,
                              hipStream_t stream) {
  const float* x = (const float*)d_in[0];
  const float* query = (const float*)d_in[1];
  const float* ref = (const float*)d_in[2];
  const float* c1_w = (const float*)d_in[3];
  const float* c1_b = (const float*)d_in[4];
  const float* r1a_w = (const float*)d_in[5];
  const float* r1a_b = (const float*)d_in[6];
  const float* r1b_w = (const float*)d_in[7];
  const float* r1b_b = (const float*)d_in[8];
  const float* p1_w = (const float*)d_in[9];
  const float* p1_b = (const float*)d_in[10];
  const float* r2a_w = (const float*)d_in[11];
  const float* r2a_b = (const float*)d_in[12];
  const float* r2b_w = (const float*)d_in[13];
  const float* r2b_b = (const float*)d_in[14];
  const float* p2_w = (const float*)d_in[15];
  const float* p2_b = (const float*)d_in[16];
  float* out = (float*)d_out;

  float* ws = (float*)d_ws;
  float* qup = ws;                     // 2*3*65536     = 393216
  float* cat = qup + 393216;           // 2*64*65536    = 8388608
  float* t1 = cat + 8388608;           // 2*32*65536    = 4194304
  float* t2 = t1 + 4194304;            // 4194304
  float* h1 = t2 + 4194304;            // 4194304
  float4* par = (float4*)(h1 + 4194304);  // 131072 float4
  float* wr_c1 = (float*)(par + 131072);  // 2400
  float* wr_r1a = wr_c1 + 2400;           // 9216
  float* wr_r1b = wr_r1a + 9216;          // 9216
  float* wr_p1 = wr_r1b + 9216;           // 51200
  float* wr_r2a = wr_p1 + 51200;          // 9216
  float* wr_r2b = wr_r2a + 9216;          // 9216

  repack_w<<<10, 256, 0, stream>>>(c1_w, wr_c1, 3, 25);
  repack_w<<<36, 256, 0, stream>>>(r1a_w, wr_r1a, 32, 9);
  repack_w<<<36, 256, 0, stream>>>(r1b_w, wr_r1b, 32, 9);
  repack_w<<<200, 256, 0, stream>>>(p1_w, wr_p1, 64, 25);
  repack_w<<<36, 256, 0, stream>>>(r2a_w, wr_r2a, 32, 9);
  repack_w<<<36, 256, 0, stream>>>(r2b_w, wr_r2b, 32, 9);

  up2_kernel<<<1536, 256, 0, stream>>>(query, qup);

  // head(ref) -> cat channels [0,32)
  conv5_c1<<<512, 256, 0, stream>>>(ref, wr_c1, c1_b, t1);
  conv3_32<false><<<512, 256, 0, stream>>>(t1, 32, wr_r1a, r1a_b, nullptr, t2, 32, 0);
  conv3_32<true><<<512, 256, 0, stream>>>(t2, 32, wr_r1b, r1b_b, t1, cat, 64, 0);

  // head(q_up) -> cat channels [32,64)
  conv5_c1<<<512, 256, 0, stream>>>(qup, wr_c1, c1_b, t1);
  conv3_32<false><<<512, 256, 0, stream>>>(t1, 32, wr_r1a, r1a_b, nullptr, t2, 32, 0);
  conv3_32<true><<<512, 256, 0, stream>>>(t2, 32, wr_r1b, r1b_b, t1, cat, 64, 32);

  // trunk
  conv5_p1<<<512, 256, 0, stream>>>(cat, wr_p1, p1_b, h1);
  conv3_32<false><<<512, 256, 0, stream>>>(h1, 32, wr_r2a, r2a_b, nullptr, t2, 32, 0);
  conv3_32<true><<<512, 256, 0, stream>>>(t2, 32, wr_r2b, r2b_b, h1, t1, 32, 0);

  // affinity params
  p2_aff<<<512, 256, 0, stream>>>(t1, p2_w, p2_b, par);

  // deformable sampling
  sample_kernel<<<512, 256, 0, stream>>>(x, par, out);
}

// Round 2
// 765.397 us; speedup vs baseline: 1.3963x; 1.3963x over previous
//
#include <hip/hip_runtime.h>
#include <math.h>

#define HW 65536

__device__ __forceinline__ float lrelu_f(float v) { return v > 0.f ? v : 0.2f * v; }

// ---- repack all weights: w[32][IC][KK] -> wr[IC][4][KK][8]  (one launch) ----
__global__ __launch_bounds__(256) void repack_all(
    const float* __restrict__ c1_w, float* __restrict__ wr_c1,
    const float* __restrict__ r1a_w, float* __restrict__ wr_r1a,
    const float* __restrict__ r1b_w, float* __restrict__ wr_r1b,
    const float* __restrict__ p1_w, float* __restrict__ wr_p1,
    const float* __restrict__ r2a_w, float* __restrict__ wr_r2a,
    const float* __restrict__ r2b_w, float* __restrict__ wr_r2b) {
  int i = blockIdx.x * 256 + threadIdx.x;
  const float* src;
  float* dst;
  int IC, KK, base;
  if (i < 2400)        { src = c1_w;  dst = wr_c1;  IC = 3;  KK = 25; base = 0; }
  else if (i < 11616)  { src = r1a_w; dst = wr_r1a; IC = 32; KK = 9;  base = 2400; }
  else if (i < 20832)  { src = r1b_w; dst = wr_r1b; IC = 32; KK = 9;  base = 11616; }
  else if (i < 72032)  { src = p1_w;  dst = wr_p1;  IC = 64; KK = 25; base = 20832; }
  else if (i < 81248)  { src = r2a_w; dst = wr_r2a; IC = 32; KK = 9;  base = 72032; }
  else if (i < 90464)  { src = r2b_w; dst = wr_r2b; IC = 32; KK = 9;  base = 81248; }
  else return;
  int j = i - base;
  int ickk = IC * KK;
  int o = j / ickk;
  int r = j - o * ickk;
  int ic = r / KK;
  int k = r - ic * KK;
  dst[((ic * 4 + (o >> 3)) * KK + k) * 8 + (o & 7)] = src[j];
}

// ---- bicubic 2x upsample: (2,3,128,128) -> (2,3,256,256) ----
__global__ __launch_bounds__(256) void up2_kernel(const float* __restrict__ q,
                                                  float* __restrict__ out) {
  int gid = blockIdx.x * blockDim.x + threadIdx.x;
  if (gid >= 2 * 3 * HW) return;
  int x = gid & 255;
  int y = (gid >> 8) & 255;
  int pc = gid >> 16;
  const float F[4] = {-0.03515625f, 0.26171875f, 0.87890625f, -0.10546875f};
  int iy[4], ix[4];
  float wy[4], wx[4];
  {
    int k = y >> 1; bool even = !(y & 1); int i0 = even ? k - 1 : k;
#pragma unroll
    for (int t = 0; t < 4; ++t) {
      int ii = i0 - 1 + t;
      iy[t] = min(max(ii, 0), 127);
      wy[t] = even ? F[t] : F[3 - t];
    }
  }
  {
    int k = x >> 1; bool even = !(x & 1); int i0 = even ? k - 1 : k;
#pragma unroll
    for (int t = 0; t < 4; ++t) {
      int ii = i0 - 1 + t;
      ix[t] = min(max(ii, 0), 127);
      wx[t] = even ? F[t] : F[3 - t];
    }
  }
  const float* qp = q + pc * 16384;
  float s = 0.f;
#pragma unroll
  for (int i = 0; i < 4; ++i) {
    float rs = 0.f;
#pragma unroll
    for (int j = 0; j < 4; ++j) rs = fmaf(wx[j], qp[iy[i] * 128 + ix[j]], rs);
    s = fmaf(wy[i], rs, s);
  }
  out[gid] = s;
}

// ============ conv kernels: 16x4 tile, 4 waves x 8oc, grid 2048 ============
// lane -> pixel: py = lane>>4 (0..3), px = lane&15 (0..15)
// LDS row stride 24 floats: 4 rows/wave at stride 24 -> banks 0,8,16,24 starts,
// width-16 intervals -> exactly 2 lanes/bank (free).

// ---- conv 5x5, IC=3 -> 32, pad 2, + lrelu ----
__global__ __launch_bounds__(256) void conv5_c1(const float* __restrict__ in,
                                                const float* __restrict__ wr,
                                                const float* __restrict__ bias,
                                                float* __restrict__ out) {
  __shared__ float sm[3][8][24];
  int blk = blockIdx.x;
  int b = blk >> 10;
  int t = blk & 1023;
  int ty0 = (t >> 4) * 4, tx0 = (t & 15) * 16;
  int tid = threadIdx.x;
  for (int i = tid; i < 3 * 160; i += 256) {
    int ic = i / 160;
    int r2 = i - ic * 160;
    int r = r2 / 20;
    int c = r2 - r * 20;
    int gy = ty0 + r - 2, gx = tx0 + c - 2;
    float v = 0.f;
    if ((unsigned)gy < 256u && (unsigned)gx < 256u) v = in[(b * 3 + ic) * HW + gy * 256 + gx];
    sm[ic][r][c] = v;
  }
  __syncthreads();
  int lane = tid & 63;
  int wv = __builtin_amdgcn_readfirstlane(tid >> 6);
  int py = lane >> 4, px = lane & 15;
  float acc[8];
#pragma unroll
  for (int o = 0; o < 8; ++o) acc[o] = bias[wv * 8 + o];
#pragma unroll
  for (int ic = 0; ic < 3; ++ic) {
    const float* wp = wr + (ic * 4 + wv) * 200;
#pragma unroll
    for (int ky = 0; ky < 5; ++ky)
#pragma unroll
      for (int kx = 0; kx < 5; ++kx) {
        float v = sm[ic][py + ky][px + kx];
        const float* w8 = wp + (ky * 5 + kx) * 8;
#pragma unroll
        for (int o = 0; o < 8; ++o) acc[o] = fmaf(v, w8[o], acc[o]);
      }
  }
  int y = ty0 + py, x = tx0 + px;
#pragma unroll
  for (int o = 0; o < 8; ++o)
    out[(b * 32 + wv * 8 + o) * HW + y * 256 + x] = lrelu_f(acc[o]);
}

// ---- conv 3x3, 32 -> 32, pad 1, optional residual, lrelu ----
template <bool RES>
__global__ __launch_bounds__(256) void conv3_32(const float* __restrict__ in, int in_cs,
                                                const float* __restrict__ wr,
                                                const float* __restrict__ bias,
                                                const float* __restrict__ res,
                                                float* __restrict__ out, int out_cs,
                                                int out_co) {
  __shared__ float sm[32][6][24];  // 18432 B -> 8 blocks/CU
  int blk = blockIdx.x;
  int b = blk >> 10;
  int t = blk & 1023;
  int ty0 = (t >> 4) * 4, tx0 = (t & 15) * 16;
  int tid = threadIdx.x;
  for (int i = tid; i < 32 * 108; i += 256) {
    int ic = i / 108;
    int r2 = i - ic * 108;
    int r = r2 / 18;
    int c = r2 - r * 18;
    int gy = ty0 + r - 1, gx = tx0 + c - 1;
    float v = 0.f;
    if ((unsigned)gy < 256u && (unsigned)gx < 256u)
      v = in[(b * in_cs + ic) * HW + gy * 256 + gx];
    sm[ic][r][c] = v;
  }
  __syncthreads();
  int lane = tid & 63;
  int wv = __builtin_amdgcn_readfirstlane(tid >> 6);
  int py = lane >> 4, px = lane & 15;
  float acc[8];
#pragma unroll
  for (int o = 0; o < 8; ++o) acc[o] = bias[wv * 8 + o];
#pragma unroll 4
  for (int ic = 0; ic < 32; ++ic) {
    const float* wp = wr + (ic * 4 + wv) * 72;
#pragma unroll
    for (int ky = 0; ky < 3; ++ky)
#pragma unroll
      for (int kx = 0; kx < 3; ++kx) {
        float v = sm[ic][py + ky][px + kx];
        const float* w8 = wp + (ky * 3 + kx) * 8;
#pragma unroll
        for (int o = 0; o < 8; ++o) acc[o] = fmaf(v, w8[o], acc[o]);
      }
  }
  int y = ty0 + py, x = tx0 + px;
  int co = out_co + wv * 8;
#pragma unroll
  for (int o = 0; o < 8; ++o) {
    float rv = acc[o];
    if (RES) rv += res[(b * 32 + wv * 8 + o) * HW + y * 256 + x];
    out[(b * out_cs + co + o) * HW + y * 256 + x] = lrelu_f(rv);
  }
}

// ---- conv 5x5, 64 -> 32, pad 2, + lrelu (two 32-ic chunks) ----
__global__ __launch_bounds__(256) void conv5_p1(const float* __restrict__ in,
                                                const float* __restrict__ wr,
                                                const float* __restrict__ bias,
                                                float* __restrict__ out) {
  __shared__ float sm[32][8][24];  // 24576 B -> 6 blocks/CU
  int blk = blockIdx.x;
  int b = blk >> 10;
  int t = blk & 1023;
  int ty0 = (t >> 4) * 4, tx0 = (t & 15) * 16;
  int tid = threadIdx.x;
  int lane = tid & 63;
  int wv = __builtin_amdgcn_readfirstlane(tid >> 6);
  int py = lane >> 4, px = lane & 15;
  float acc[8];
#pragma unroll
  for (int o = 0; o < 8; ++o) acc[o] = bias[wv * 8 + o];
#pragma unroll
  for (int ch = 0; ch < 2; ++ch) {
    __syncthreads();
    for (int i = tid; i < 32 * 160; i += 256) {
      int ic = i / 160;
      int r2 = i - ic * 160;
      int r = r2 / 20;
      int c = r2 - r * 20;
      int gy = ty0 + r - 2, gx = tx0 + c - 2;
      float v = 0.f;
      if ((unsigned)gy < 256u && (unsigned)gx < 256u)
        v = in[(b * 64 + ch * 32 + ic) * HW + gy * 256 + gx];
      sm[ic][r][c] = v;
    }
    __syncthreads();
#pragma unroll 2
    for (int ic = 0; ic < 32; ++ic) {
      const float* wp = wr + ((ch * 32 + ic) * 4 + wv) * 200;
#pragma unroll
      for (int ky = 0; ky < 5; ++ky)
#pragma unroll
        for (int kx = 0; kx < 5; ++kx) {
          float v = sm[ic][py + ky][px + kx];
          const float* w8 = wp + (ky * 5 + kx) * 8;
#pragma unroll
          for (int o = 0; o < 8; ++o) acc[o] = fmaf(v, w8[o], acc[o]);
        }
    }
  }
  int y = ty0 + py, x = tx0 + px;
#pragma unroll
  for (int o = 0; o < 8; ++o)
    out[(b * 32 + wv * 8 + o) * HW + y * 256 + x] = lrelu_f(acc[o]);
}

// ---- 1x1 conv 32->3, +1, clip, -> per-pixel sampling params ----
__global__ __launch_bounds__(256) void p2_aff(const float* __restrict__ h2,
                                              const float* __restrict__ w,
                                              const float* __restrict__ bias,
                                              float4* __restrict__ par) {
  int gid = blockIdx.x * 256 + threadIdx.x;  // 131072
  int b = gid >> 16;
  int p = gid & 65535;
  float a0 = bias[0], a1 = bias[1], a2 = bias[2];
  for (int c = 0; c < 32; ++c) {
    float v = h2[(b * 32 + c) * HW + p];
    a0 = fmaf(v, w[c], a0);
    a1 = fmaf(v, w[32 + c], a1);
    a2 = fmaf(v, w[64 + c], a2);
  }
  a0 = fminf(fmaxf(a0 + 1.f, -3.f), 3.f);
  a1 = fminf(fmaxf(a1 + 1.f, -3.f), 3.f);
  a2 = fminf(fmaxf(a2 + 1.f, -3.f), 3.f);
  float th = (a2 - 1.f) * 1.0472f;
  float4 o;
  o.x = a0;
  o.y = a1;
  o.z = cosf(th);
  o.w = sinf(th);
  par[gid] = o;
}

__device__ __forceinline__ int refl_idx(int k) {
  int s = k - 1;
  s = s < 0 ? -s : s;
  s = s > 255 ? 510 - s : s;
  return s;
}

// ---- deformable sampling, output-element-parallel (coalesced writes) ----
__global__ __launch_bounds__(256) void sample_kernel(const float* __restrict__ x,
                                                     const float4* __restrict__ par,
                                                     float* __restrict__ out) {
  const int total = 2 * 32 * 768 * 768;
  int stride = gridDim.x * 256;
  for (int gid = blockIdx.x * 256 + threadIdx.x; gid < total; gid += stride) {
    int ox = gid % 768;
    int t1 = gid / 768;
    int oy = t1 % 768;
    int t2 = t1 / 768;
    int c = t2 & 31;
    int b = t2 >> 5;
    int xw = ox / 3;
    int kj = ox - 3 * xw;
    int y = oy / 3;
    int ki = oy - 3 * y;
    float4 pr = par[(b << 16) + y * 256 + xw];
    float px0 = ((float)ki - 1.5f) * pr.x;
    float py0 = ((float)kj - 1.5f) * pr.y;
    float ct = pr.z, st = pr.w;
    float px = px0 * ct - py0 * st + 1.5f + (float)(y + 1);
    float py = px0 * st + py0 * ct + 1.5f + (float)(xw + 1);
    float fx = floorf(px), fy = floorf(py);
    float x0f = fminf(fmaxf(fx, 0.f), 257.f);
    float x1f = fminf(fmaxf(fx + 1.f, 0.f), 257.f);
    float y0f = fminf(fmaxf(fy, 0.f), 257.f);
    float y1f = fminf(fmaxf(fy + 1.f, 0.f), 257.f);
    float pxc = fminf(fmaxf(px, 0.f), 257.f);
    float pyc = fminf(fmaxf(py, 0.f), 257.f);
    float dx0 = 1.f + (x0f - pxc), dx1 = 1.f - (x1f - pxc);
    float dy0 = 1.f + (y0f - pyc), dy1 = 1.f - (y1f - pyc);
    int xi0 = refl_idx((int)x0f), xi1 = refl_idx((int)x1f);
    int yi0 = refl_idx((int)y0f), yi1 = refl_idx((int)y1f);
    const float* xp = x + (size_t)(b * 32 + c) * HW;
    float v = dx0 * dy0 * xp[xi0 * 256 + yi0] + dx1 * dy1 * xp[xi1 * 256 + yi1] +
              dx0 * dy1 * xp[xi0 * 256 + yi1] + dx1 * dy0 * xp[xi1 * 256 + yi0];
    out[gid] = v;
  }
}

extern "C" void kernel_launch(void* const* d_in, const int* in_sizes, int n_in,
                              void* d_out, int out_size, void* d_ws, size_t ws_size,
                              hipStream_t stream) {
  const float* x = (const float*)d_in[0];
  const float* query = (const float*)d_in[1];
  const float* ref = (const float*)d_in[2];
  const float* c1_w = (const float*)d_in[3];
  const float* c1_b = (const float*)d_in[4];
  const float* r1a_w = (const float*)d_in[5];
  const float* r1a_b = (const float*)d_in[6];
  const float* r1b_w = (const float*)d_in[7];
  const float* r1b_b = (const float*)d_in[8];
  const float* p1_w = (const float*)d_in[9];
  const float* p1_b = (const float*)d_in[10];
  const float* r2a_w = (const float*)d_in[11];
  const float* r2a_b = (const float*)d_in[12];
  const float* r2b_w = (const float*)d_in[13];
  const float* r2b_b = (const float*)d_in[14];
  const float* p2_w = (const float*)d_in[15];
  const float* p2_b = (const float*)d_in[16];
  float* out = (float*)d_out;

  float* ws = (float*)d_ws;
  float* qup = ws;                        // 393216
  float* cat = qup + 393216;              // 8388608
  float* t1 = cat + 8388608;              // 4194304
  float* t2 = t1 + 4194304;               // 4194304
  float* h1 = t2 + 4194304;               // 4194304
  float4* par = (float4*)(h1 + 4194304);  // 131072 float4
  float* wr_c1 = (float*)(par + 131072);  // 2400
  float* wr_r1a = wr_c1 + 2400;           // 9216
  float* wr_r1b = wr_r1a + 9216;          // 9216
  float* wr_p1 = wr_r1b + 9216;           // 51200
  float* wr_r2a = wr_p1 + 51200;          // 9216
  float* wr_r2b = wr_r2a + 9216;          // 9216

  repack_all<<<354, 256, 0, stream>>>(c1_w, wr_c1, r1a_w, wr_r1a, r1b_w, wr_r1b,
                                      p1_w, wr_p1, r2a_w, wr_r2a, r2b_w, wr_r2b);

  up2_kernel<<<1536, 256, 0, stream>>>(query, qup);

  // head(ref) -> cat channels [0,32)
  conv5_c1<<<2048, 256, 0, stream>>>(ref, wr_c1, c1_b, t1);
  conv3_32<false><<<2048, 256, 0, stream>>>(t1, 32, wr_r1a, r1a_b, nullptr, t2, 32, 0);
  conv3_32<true><<<2048, 256, 0, stream>>>(t2, 32, wr_r1b, r1b_b, t1, cat, 64, 0);

  // head(q_up) -> cat channels [32,64)
  conv5_c1<<<2048, 256, 0, stream>>>(qup, wr_c1, c1_b, t1);
  conv3_32<false><<<2048, 256, 0, stream>>>(t1, 32, wr_r1a, r1a_b, nullptr, t2, 32, 0);
  conv3_32<true><<<2048, 256, 0, stream>>>(t2, 32, wr_r1b, r1b_b, t1, cat, 64, 32);

  // trunk
  conv5_p1<<<2048, 256, 0, stream>>>(cat, wr_p1, p1_b, h1);
  conv3_32<false><<<2048, 256, 0, stream>>>(h1, 32, wr_r2a, r2a_b, nullptr, t2, 32, 0);
  conv3_32<true><<<2048, 256, 0, stream>>>(t2, 32, wr_r2b, r2b_b, h1, t1, 32, 0);

  // affinity params
  p2_aff<<<512, 256, 0, stream>>>(t1, p2_w, p2_b, par);

  // deformable sampling
  sample_kernel<<<4096, 256, 0, stream>>>(x, par, out);
}